// Round 5
// baseline (629.460 us; speedup 1.0000x reference)
//
#include <hip/hip_runtime.h>
#include <hip/hip_cooperative_groups.h>

namespace cg = cooperative_groups;

// x: (2048, 200, 11, 11) f32.  NQUAD = N/4 = 12,390,400 float4 quads.
// out = exp(-(x-center)^2/S - (|i-5|+|j-5|)/2),  S = global sum of (x-center)^2.
//
// R5: single cooperative kernel. Read x ONCE; hold sq on-chip as packed bf16
// (80 reg-quads + 15 LDS-quads per thread); grid.sync for S; emit out.
// HBM traffic 594 MB -> 396 MB.  bf16-sq error bound: max_u u*e^-u * 2^-9
// ~= 7e-4 absolute worst-case (3e-9 on this data) << 2e-2 threshold.

#define NQUAD      12390400
#define PLANE      121
#define CENTER_OFF 60
#define NBLK       256
#define NTHR       512
#define TTOT       (NBLK * NTHR)          // 131072 threads
#define QFULL      (NQUAD / TTOT)         // 94 full quads/thread
#define QREM       (NQUAD - QFULL * TTOT) // 69632 tail quads (fid < QREM)
#define LDSQ       15                     // quads/thread held in LDS
#define REGQ       (QFULL - LDSQ)         // 79 full reg quads (+1 tail slot)

typedef float f32x4 __attribute__((ext_vector_type(4)));

__device__ __forceinline__ uint32_t pack2_bf16(float a, float b) {
    uint32_t ua = __float_as_uint(a);
    uint32_t ub = __float_as_uint(b);
    ua += 0x7FFFu + ((ua >> 16) & 1u);   // RNE to bf16
    ub += 0x7FFFu + ((ub >> 16) & 1u);
    return (ua >> 16) | (ub & 0xFFFF0000u);
}
__device__ __forceinline__ float unpk_lo(uint32_t p) { return __uint_as_float(p << 16); }
__device__ __forceinline__ float unpk_hi(uint32_t p) { return __uint_as_float(p & 0xFFFF0000u); }

__global__ __launch_bounds__(NTHR, 2) void fuzzy_coop_kernel(
    const float* __restrict__ x, float* __restrict__ out, float* __restrict__ ws)
{
    __shared__ uint2 lds_sq[LDSQ][NTHR];   // 61,440 B
    __shared__ float dist_half[PLANE];     // 484 B
    __shared__ float red[NTHR / 64];       // 32 B
    __shared__ float s_inv;

    const int tid = threadIdx.x;
    const int fid = blockIdx.x * NTHR + tid;

    if (tid < PLANE) {
        int i = tid / 11, j = tid % 11;
        dist_half[tid] = 0.5f * (fabsf((float)(i - 5)) + fabsf((float)(j - 5)));
    }

    float acc = 0.0f;
    uint2 rq[REGQ + 1];   // statically indexed only (full unroll) -> stays in VGPRs

    auto do_quad = [&](int q) -> uint2 {
        int gq   = q * TTOT + fid;
        f32x4 v  = reinterpret_cast<const f32x4*>(x)[gq];
        int base = gq * 4;
        int p0   = base / PLANE;                    // magic-mul
        int bnd  = (p0 + 1) * PLANE;
        float cv0 = x[p0 * PLANE + CENTER_OFF];     // L1 broadcast
        float cv3 = x[((base + 3) / PLANE) * PLANE + CENTER_OFF];
        float d0 = v[0] - cv0;                      // base < bnd always
        float d1 = v[1] - ((base + 1 >= bnd) ? cv3 : cv0);
        float d2 = v[2] - ((base + 2 >= bnd) ? cv3 : cv0);
        float d3 = v[3] - ((base + 3 >= bnd) ? cv3 : cv0);
        float s0 = d0 * d0, s1 = d1 * d1, s2 = d2 * d2, s3 = d3 * d3;
        acc += (s0 + s1) + (s2 + s3);
        uint2 pkt;
        pkt.x = pack2_bf16(s0, s1);
        pkt.y = pack2_bf16(s2, s3);
        return pkt;
    };

    // ---- phase 1: read x once, hold packed sq on-chip, accumulate S ----
    for (int q = 0; q < LDSQ; ++q)          // runtime idx ok: LDS
        lds_sq[q][tid] = do_quad(q);
    #pragma unroll
    for (int q = 0; q < REGQ; ++q)          // static idx: registers
        rq[q] = do_quad(LDSQ + q);
    if (fid < QREM) {
        rq[REGQ] = do_quad(QFULL);
    } else {
        rq[REGQ].x = 0u; rq[REGQ].y = 0u;
    }

    // block reduction of acc
    #pragma unroll
    for (int off = 32; off > 0; off >>= 1)
        acc += __shfl_down(acc, off, 64);
    if ((tid & 63) == 0) red[tid >> 6] = acc;
    __syncthreads();
    if (tid == 0) {
        float s = 0.0f;
        #pragma unroll
        for (int w = 0; w < NTHR / 64; ++w) s += red[w];
        ws[blockIdx.x] = s;
    }

    __threadfence();            // release partials (device scope)
    cg::this_grid().sync();
    __threadfence();            // acquire (invalidate stale lines cross-XCD)

    // ---- global sum of the 256 partials (every block redundantly) ----
    float s = (tid < NBLK) ? ws[tid] : 0.0f;
    #pragma unroll
    for (int off = 32; off > 0; off >>= 1)
        s += __shfl_down(s, off, 64);
    __syncthreads();            // red[] reuse barrier
    if ((tid & 63) == 0) red[tid >> 6] = s;
    __syncthreads();
    if (tid == 0) {
        float t = 0.0f;
        #pragma unroll
        for (int w = 0; w < NTHR / 64; ++w) t += red[w];
        s_inv = 1.0f / t;
    }
    __syncthreads();
    const float invS = s_inv;

    // ---- phase 2: emit out = exp(-sq*invS - dist/2) from held sq ----
    auto emit_quad = [&](int q, uint2 pkt) {
        int gq     = q * TTOT + fid;
        int base   = gq * 4;
        int p0     = base / PLANE;
        int start0 = p0 * PLANE;
        int bnd    = start0 + PLANE;
        int w0 = base - start0;
        int w1 = base + 1 - ((base + 1 >= bnd) ? bnd : start0);
        int w2 = base + 2 - ((base + 2 >= bnd) ? bnd : start0);
        int w3 = base + 3 - ((base + 3 >= bnd) ? bnd : start0);
        f32x4 r;
        r[0] = __expf(fmaf(-unpk_lo(pkt.x), invS, -dist_half[w0]));
        r[1] = __expf(fmaf(-unpk_hi(pkt.x), invS, -dist_half[w1]));
        r[2] = __expf(fmaf(-unpk_lo(pkt.y), invS, -dist_half[w2]));
        r[3] = __expf(fmaf(-unpk_hi(pkt.y), invS, -dist_half[w3]));
        reinterpret_cast<f32x4*>(out)[gq] = r;
    };

    for (int q = 0; q < LDSQ; ++q)
        emit_quad(q, lds_sq[q][tid]);
    #pragma unroll
    for (int q = 0; q < REGQ; ++q)
        emit_quad(LDSQ + q, rq[q]);
    if (fid < QREM)
        emit_quad(QFULL, rq[REGQ]);
}

extern "C" void kernel_launch(void* const* d_in, const int* in_sizes, int n_in,
                              void* d_out, int out_size, void* d_ws, size_t ws_size,
                              hipStream_t stream)
{
    const float* x   = (const float*)d_in[0];
    float*       out = (float*)d_out;
    float*       ws  = (float*)d_ws;      // 256 floats of partials

    void* args[] = { (void*)&x, (void*)&out, (void*)&ws };
    hipLaunchCooperativeKernel((const void*)fuzzy_coop_kernel,
                               dim3(NBLK), dim3(NTHR), args, 0, stream);
}